// Round 1
// baseline (164.083 us; speedup 1.0000x reference)
//
#include <hip/hip_runtime.h>
#include <hip/hip_bf16.h>
#include <stdint.h>

#define C_DIM 512
#define T_SEQ 8192
#define N_PROP 16384
#define HID_DIM 1024
#define OUT_DIM 512
#define K2C 1024  // 2*C

typedef __attribute__((ext_vector_type(8))) __bf16 bf16x8;
typedef __attribute__((ext_vector_type(4))) float f32x4;

// ---------------- cumsum: one wave per channel, shuffle scan ----------------
__global__ __launch_bounds__(64) void cumsum_kernel(const float* __restrict__ feat,
                                                    float* __restrict__ cs_row) {
    int c = blockIdx.x;
    const float* in = feat + (size_t)c * T_SEQ;
    float* out = cs_row + (size_t)c * (T_SEQ + 1);
    int lane = threadIdx.x;
    if (lane == 0) out[0] = 0.0f;
    float carry = 0.0f;
    for (int i0 = 0; i0 < T_SEQ; i0 += 64) {
        float x = in[i0 + lane];
#pragma unroll
        for (int s = 1; s < 64; s <<= 1) {
            float y = __shfl_up(x, s);
            if (lane >= s) x += y;
        }
        out[i0 + lane + 1] = carry + x;
        carry += __shfl(x, 63);
    }
}

// ---------------- transpose cs (C, T+1) -> (T+1, C) ----------------
__global__ __launch_bounds__(256) void transpose_kernel(const float* __restrict__ cs_row,
                                                        float* __restrict__ cs_t) {
    __shared__ float tl[32][33];
    int tx = threadIdx.x, ty = threadIdx.y;  // (32, 8)
    int x0 = blockIdx.x * 32;                // t index
    int y0 = blockIdx.y * 32;                // channel
#pragma unroll
    for (int i = 0; i < 32; i += 8) {
        int x = x0 + tx;
        int y = y0 + ty + i;
        if (x <= T_SEQ) tl[ty + i][tx] = cs_row[(size_t)y * (T_SEQ + 1) + x];
    }
    __syncthreads();
#pragma unroll
    for (int i = 0; i < 32; i += 8) {
        int t = x0 + ty + i;
        int c = y0 + tx;
        if (t <= T_SEQ) cs_t[(size_t)t * C_DIM + c] = tl[tx][ty + i];
    }
}

// ---------------- pooling -> e (N, 2C) bf16 ----------------
__global__ __launch_bounds__(512) void pool_kernel(const float* __restrict__ cs_t,
                                                   const int* __restrict__ lptr,
                                                   const int* __restrict__ rptr,
                                                   __hip_bfloat16* __restrict__ e) {
    int n = blockIdx.x;
    int li = lptr[n], ri = rptr[n];
    float w = fmaxf((float)(ri - li), 1.0f);
    int bw = max(1, (int)(0.15f * w));
    int lb_s = max(0, li - bw);
    int lb_e = min(T_SEQ, li + bw);
    int rb_s = max(0, ri - bw);
    int rb_e = min(T_SEQ, ri + bw);
    // _pool clamps: e = min(max(s+1, e), T)
    lb_e = min(max(lb_s + 1, lb_e), T_SEQ);
    rb_e = min(max(rb_s + 1, rb_e), T_SEQ);
    int c = threadIdx.x;  // 512 threads
    float sl = cs_t[(size_t)lb_e * C_DIM + c] - cs_t[(size_t)lb_s * C_DIM + c];
    float sr = cs_t[(size_t)rb_e * C_DIM + c] - cs_t[(size_t)rb_s * C_DIM + c];
    float el = sl / (float)(lb_e - lb_s);
    float er = sr / (float)(rb_e - rb_s);
    e[(size_t)n * K2C + c] = __float2bfloat16(el);
    e[(size_t)n * K2C + C_DIM + c] = __float2bfloat16(er);
}

// ---------------- fp32 -> bf16 convert ----------------
__global__ __launch_bounds__(256) void cvt_bf16_kernel(const float* __restrict__ src,
                                                       __hip_bfloat16* __restrict__ dst, int n) {
    int i = blockIdx.x * 256 + threadIdx.x;
    if (i < n) dst[i] = __float2bfloat16(src[i]);
}

// ---------------- GEMM: C[m][n] = sum_k A[m][k]*B[n][k] (+bias, opt relu) ----------------
// A: (M, K) bf16 row-major. B: (Nc, K) bf16 row-major. 128x128 tile, BK=32,
// 4 waves (2x2), each wave 64x64 = 4x4 fragments of 16x16x32.
template <int WRITE_BF16_RELU>
__global__ __launch_bounds__(256) void gemm_bt_kernel(const __hip_bfloat16* __restrict__ A,
                                                      const __hip_bfloat16* __restrict__ B,
                                                      const float* __restrict__ bias,
                                                      void* __restrict__ Cout, int Nc, int K) {
    __shared__ __align__(16) __hip_bfloat16 As[128 * 32];
    __shared__ __align__(16) __hip_bfloat16 Bs[128 * 32];
    const int tid = threadIdx.x;
    const int lane = tid & 63;
    const int wid = tid >> 6;
    const int wm = wid >> 1, wn = wid & 1;
    const long m0 = (long)blockIdx.x * 128;
    const long n0 = (long)blockIdx.y * 128;

    const int ldr = tid >> 2;  // staging row within 64-row group
    const int kq = tid & 3;    // 16B chunk within the 64B row

    const int fr = lane & 15;
    const int fk = (lane >> 4) * 8;  // K element offset of this lane's fragment

    f32x4 acc[4][4] = {};

    for (int k0 = 0; k0 < K; k0 += 32) {
        __builtin_amdgcn_global_load_lds(
            (const __attribute__((address_space(1))) void*)(A + (m0 + ldr) * K + k0 + kq * 8),
            (__attribute__((address_space(3))) void*)(As + tid * 8), 16, 0, 0);
        __builtin_amdgcn_global_load_lds(
            (const __attribute__((address_space(1))) void*)(A + (m0 + 64 + ldr) * K + k0 + kq * 8),
            (__attribute__((address_space(3))) void*)(As + 2048 + tid * 8), 16, 0, 0);
        __builtin_amdgcn_global_load_lds(
            (const __attribute__((address_space(1))) void*)(B + (n0 + ldr) * K + k0 + kq * 8),
            (__attribute__((address_space(3))) void*)(Bs + tid * 8), 16, 0, 0);
        __builtin_amdgcn_global_load_lds(
            (const __attribute__((address_space(1))) void*)(B + (n0 + 64 + ldr) * K + k0 + kq * 8),
            (__attribute__((address_space(3))) void*)(Bs + 2048 + tid * 8), 16, 0, 0);
        __syncthreads();

        bf16x8 af[4], bfr[4];
#pragma unroll
        for (int i = 0; i < 4; ++i)
            af[i] = *(const bf16x8*)(As + (wm * 64 + i * 16 + fr) * 32 + fk);
#pragma unroll
        for (int j = 0; j < 4; ++j)
            bfr[j] = *(const bf16x8*)(Bs + (wn * 64 + j * 16 + fr) * 32 + fk);
#pragma unroll
        for (int i = 0; i < 4; ++i)
#pragma unroll
            for (int j = 0; j < 4; ++j)
                acc[i][j] = __builtin_amdgcn_mfma_f32_16x16x32_bf16(af[i], bfr[j], acc[i][j], 0, 0, 0);
        __syncthreads();
    }

    const int rq = (lane >> 4) * 4;
    if (WRITE_BF16_RELU) {
        __hip_bfloat16* Co = (__hip_bfloat16*)Cout;
#pragma unroll
        for (int i = 0; i < 4; ++i)
#pragma unroll
            for (int j = 0; j < 4; ++j)
#pragma unroll
                for (int q = 0; q < 4; ++q) {
                    long m = m0 + wm * 64 + i * 16 + rq + q;
                    long n = n0 + wn * 64 + j * 16 + fr;
                    float v = acc[i][j][q] + bias[n];
                    v = fmaxf(v, 0.0f);
                    Co[m * Nc + n] = __float2bfloat16(v);
                }
    } else {
        float* Co = (float*)Cout;
#pragma unroll
        for (int i = 0; i < 4; ++i)
#pragma unroll
            for (int j = 0; j < 4; ++j)
#pragma unroll
                for (int q = 0; q < 4; ++q) {
                    long m = m0 + wm * 64 + i * 16 + rq + q;
                    long n = n0 + wn * 64 + j * 16 + fr;
                    Co[m * Nc + n] = acc[i][j][q] + bias[n];
                }
    }
}

extern "C" void kernel_launch(void* const* d_in, const int* in_sizes, int n_in,
                              void* d_out, int out_size, void* d_ws, size_t ws_size,
                              hipStream_t stream) {
    const float* feat = (const float*)d_in[0];
    const int* l = (const int*)d_in[1];
    const int* r = (const int*)d_in[2];
    // d_in[3] = T scalar (fixed 8192)
    const float* W1 = (const float*)d_in[4];
    const float* b1 = (const float*)d_in[5];
    const float* W2 = (const float*)d_in[6];
    const float* b2 = (const float*)d_in[7];

    char* ws = (char*)d_ws;
    // layout (bytes):
    //   cs_t   : [0, 16779264)                  (8193*512*4)
    //   e      : [16779264, 50333696)           (16384*1024*2)
    //   h      : [50333696, 83888128)           (16384*1024*2)  -- aliased with cs_row
    //   cs_row : [50333696, 67112960)           (512*8193*4)    dead before h written
    //   W1b    : [83888128, 85985280)           (1024*1024*2)
    //   W2b    : [85985280, 87033856)           (512*1024*2)
    float* cs_t = (float*)ws;
    __hip_bfloat16* e = (__hip_bfloat16*)(ws + 16779264);
    __hip_bfloat16* h = (__hip_bfloat16*)(ws + 50333696);
    float* cs_row = (float*)(ws + 50333696);
    __hip_bfloat16* W1b = (__hip_bfloat16*)(ws + 83888128);
    __hip_bfloat16* W2b = (__hip_bfloat16*)(ws + 85985280);

    cvt_bf16_kernel<<<dim3((HID_DIM * K2C + 255) / 256), 256, 0, stream>>>(W1, W1b, HID_DIM * K2C);
    cvt_bf16_kernel<<<dim3((OUT_DIM * HID_DIM + 255) / 256), 256, 0, stream>>>(W2, W2b, OUT_DIM * HID_DIM);
    cumsum_kernel<<<dim3(C_DIM), 64, 0, stream>>>(feat, cs_row);
    transpose_kernel<<<dim3((T_SEQ + 32) / 32, C_DIM / 32), dim3(32, 8), 0, stream>>>(cs_row, cs_t);
    pool_kernel<<<dim3(N_PROP), 512, 0, stream>>>(cs_t, l, r, e);
    gemm_bt_kernel<1><<<dim3(N_PROP / 128, HID_DIM / 128), 256, 0, stream>>>(e, W1b, b1, h, HID_DIM, K2C);
    gemm_bt_kernel<0><<<dim3(N_PROP / 128, OUT_DIM / 128), 256, 0, stream>>>(h, W2b, b2, d_out, OUT_DIM, HID_DIM);
}

// Round 2
// 132.131 us; speedup vs baseline: 1.2418x; 1.2418x over previous
//
#include <hip/hip_runtime.h>
#include <hip/hip_bf16.h>
#include <stdint.h>

#define C_DIM 512
#define T_SEQ 8192
#define N_PROP 16384
#define HID_DIM 1024
#define OUT_DIM 512
#define K2C 1024  // 2*C

typedef __attribute__((ext_vector_type(8))) __bf16 bf16x8;
typedef __attribute__((ext_vector_type(4))) float f32x4;

// ---------------- cumsum: one wave per channel, float4 chunks, shuffle scan ----------------
// Writes INCLUSIVE sums (no leading zero); transpose adds the shift.
__global__ __launch_bounds__(64) void cumsum_kernel(const float* __restrict__ feat,
                                                    float* __restrict__ cs_inc) {
    int c = blockIdx.x;
    const float4* in = (const float4*)(feat + (size_t)c * T_SEQ);
    float4* out = (float4*)(cs_inc + (size_t)c * T_SEQ);
    int lane = threadIdx.x;
    float carry = 0.0f;
    for (int i0 = 0; i0 < T_SEQ / 4; i0 += 64) {
        float4 v = in[i0 + lane];
        float s1 = v.x + v.y;
        float s2 = s1 + v.z;
        float s3 = s2 + v.w;
        float x = s3;
#pragma unroll
        for (int s = 1; s < 64; s <<= 1) {
            float y = __shfl_up(x, s);
            if (lane >= s) x += y;
        }
        float base = carry + (x - s3);  // exclusive prefix of this lane's chunk
        float4 o;
        o.x = base + v.x; o.y = base + s1; o.z = base + s2; o.w = base + s3;
        out[i0 + lane] = o;
        carry += __shfl(x, 63);
    }
}

// ---------------- transpose cs_inc (C, T) -> cs_t (T+1, C) with leading-zero shift ----------------
__global__ __launch_bounds__(256) void transpose_kernel(const float* __restrict__ cs_inc,
                                                        float* __restrict__ cs_t) {
    __shared__ float tl[32][33];
    int tx = threadIdx.x, ty = threadIdx.y;  // (32, 8)
    int x0 = blockIdx.x * 32;                // t index 0..8192
    int y0 = blockIdx.y * 32;                // channel
#pragma unroll
    for (int i = 0; i < 32; i += 8) {
        int t = x0 + tx;
        int ch = y0 + ty + i;
        float v = 0.0f;
        if (t >= 1 && t <= T_SEQ) v = cs_inc[(size_t)ch * T_SEQ + (t - 1)];
        tl[ty + i][tx] = v;
    }
    __syncthreads();
#pragma unroll
    for (int i = 0; i < 32; i += 8) {
        int t = x0 + ty + i;
        int ch = y0 + tx;
        if (t <= T_SEQ) cs_t[(size_t)t * C_DIM + ch] = tl[tx][ty + i];
    }
}

// ---------------- pooling -> e (N, 2C) bf16 ----------------
__global__ __launch_bounds__(512) void pool_kernel(const float* __restrict__ cs_t,
                                                   const int* __restrict__ lptr,
                                                   const int* __restrict__ rptr,
                                                   __hip_bfloat16* __restrict__ e) {
    int n = blockIdx.x;
    int li = lptr[n], ri = rptr[n];
    float w = fmaxf((float)(ri - li), 1.0f);
    int bw = max(1, (int)(0.15f * w));
    int lb_s = max(0, li - bw);
    int lb_e = min(T_SEQ, li + bw);
    int rb_s = max(0, ri - bw);
    int rb_e = min(T_SEQ, ri + bw);
    lb_e = min(max(lb_s + 1, lb_e), T_SEQ);
    rb_e = min(max(rb_s + 1, rb_e), T_SEQ);
    int c = threadIdx.x;  // 512 threads
    float sl = cs_t[(size_t)lb_e * C_DIM + c] - cs_t[(size_t)lb_s * C_DIM + c];
    float sr = cs_t[(size_t)rb_e * C_DIM + c] - cs_t[(size_t)rb_s * C_DIM + c];
    float el = sl / (float)(lb_e - lb_s);
    float er = sr / (float)(rb_e - rb_s);
    e[(size_t)n * K2C + c] = __float2bfloat16(el);
    e[(size_t)n * K2C + C_DIM + c] = __float2bfloat16(er);
}

// ---------------- fused fp32 -> bf16 convert for W1 and W2 ----------------
__global__ __launch_bounds__(256) void cvt_bf16_kernel(const float* __restrict__ W1,
                                                       const float* __restrict__ W2,
                                                       __hip_bfloat16* __restrict__ W1b,
                                                       __hip_bfloat16* __restrict__ W2b) {
    const int n1 = HID_DIM * K2C;            // 1048576
    int i = (blockIdx.x * 256 + threadIdx.x) * 4;
    const float* src;
    __hip_bfloat16* dst;
    int j;
    if (i < n1) { src = W1; dst = W1b; j = i; }
    else        { src = W2; dst = W2b; j = i - n1; }
    float4 v = *(const float4*)(src + j);
    __hip_bfloat16 h0 = __float2bfloat16(v.x);
    __hip_bfloat16 h1 = __float2bfloat16(v.y);
    __hip_bfloat16 h2 = __float2bfloat16(v.z);
    __hip_bfloat16 h3 = __float2bfloat16(v.w);
    ushort4 u;
    u.x = *(unsigned short*)&h0; u.y = *(unsigned short*)&h1;
    u.z = *(unsigned short*)&h2; u.w = *(unsigned short*)&h3;
    *(ushort4*)(dst + j) = u;
}

// ---------------- 2-phase double-buffered GEMM ----------------
// C[m][n] = sum_k A[m][k]*B[n][k] (+bias, optional relu->bf16).
// BM x BN tile, BK=64, 512 threads = 8 waves arranged WM x WN.
// One __syncthreads per K-tile; next tile staged via global_load_lds BEFORE
// compute so the (implicit) vmcnt(0) at the barrier is nearly free.
template <int BM, int BN, int WM, int WN, int RELU_BF16>
__global__ __launch_bounds__(512, 2) void gemm2p_kernel(const __hip_bfloat16* __restrict__ A,
                                                        const __hip_bfloat16* __restrict__ B,
                                                        const float* __restrict__ bias,
                                                        void* __restrict__ Cout,
                                                        int Nc, int K, int NBlk) {
    constexpr int BK = 64;
    constexpr int WMT = BM / WM;   // wave tile rows
    constexpr int WNT = BN / WN;   // wave tile cols
    constexpr int MR = WMT / 16;
    constexpr int NR = WNT / 16;
    constexpr int nA = (BM * BK) / (512 * 8);  // gload_lds rounds for A (16B/thread each)
    constexpr int nB = (BN * BK) / (512 * 8);

    __shared__ __align__(16) __hip_bfloat16 As[2][BM * BK];
    __shared__ __align__(16) __hip_bfloat16 Bs[2][BN * BK];

    const int tid = threadIdx.x;
    const int lane = tid & 63;
    const int wid = tid >> 6;
    const int wm = wid / WN;
    const int wn = wid % WN;

    // XCD-aware bijective swizzle (gridDim.x % 8 == 0 for both GEMMs here)
    const int nwg = gridDim.x;
    const int wg = (blockIdx.x & 7) * (nwg >> 3) + (blockIdx.x >> 3);
    const long m0 = (long)(wg / NBlk) * BM;
    const long n0 = (long)(wg % NBlk) * BN;

    const int srow = tid >> 3;     // staging row within 64-row group
    const int schunk = tid & 7;    // 16B chunk within 128B row
    const int fr = lane & 15;
    const int fk = (lane >> 4) * 8;

    f32x4 acc[MR][NR] = {};

    auto stage = [&](int s, int k0) {
#pragma unroll
        for (int i = 0; i < nA; ++i)
            __builtin_amdgcn_global_load_lds(
                (const __attribute__((address_space(1))) void*)(A + (m0 + i * 64 + srow) * K + k0 + schunk * 8),
                (__attribute__((address_space(3))) void*)(&As[s][i * 4096 + tid * 8]), 16, 0, 0);
#pragma unroll
        for (int i = 0; i < nB; ++i)
            __builtin_amdgcn_global_load_lds(
                (const __attribute__((address_space(1))) void*)(B + (n0 + i * 64 + srow) * K + k0 + schunk * 8),
                (__attribute__((address_space(3))) void*)(&Bs[s][i * 4096 + tid * 8]), 16, 0, 0);
    };

    const int NT = K / BK;
    stage(0, 0);
    __syncthreads();
    for (int t = 0; t < NT; ++t) {
        const int cur = t & 1;
        if (t + 1 < NT) stage(cur ^ 1, (t + 1) * BK);
#pragma unroll
        for (int kk = 0; kk < 2; ++kk) {
            bf16x8 af[MR], bv[NR];
#pragma unroll
            for (int m = 0; m < MR; ++m)
                af[m] = *(const bf16x8*)(&As[cur][(wm * WMT + m * 16 + fr) * BK + kk * 32 + fk]);
#pragma unroll
            for (int n = 0; n < NR; ++n)
                bv[n] = *(const bf16x8*)(&Bs[cur][(wn * WNT + n * 16 + fr) * BK + kk * 32 + fk]);
#pragma unroll
            for (int m = 0; m < MR; ++m)
#pragma unroll
                for (int n = 0; n < NR; ++n)
                    acc[m][n] = __builtin_amdgcn_mfma_f32_16x16x32_bf16(af[m], bv[n], acc[m][n], 0, 0, 0);
        }
        __syncthreads();
    }

    const int rq = (lane >> 4) * 4;
#pragma unroll
    for (int m = 0; m < MR; ++m)
#pragma unroll
        for (int n = 0; n < NR; ++n) {
            long col = n0 + wn * WNT + n * 16 + fr;
            float bb = bias[col];
#pragma unroll
            for (int q = 0; q < 4; ++q) {
                long row = m0 + wm * WMT + m * 16 + rq + q;
                float v = acc[m][n][q] + bb;
                if (RELU_BF16) {
                    v = fmaxf(v, 0.0f);
                    ((__hip_bfloat16*)Cout)[row * Nc + col] = __float2bfloat16(v);
                } else {
                    ((float*)Cout)[row * Nc + col] = v;
                }
            }
        }
}

extern "C" void kernel_launch(void* const* d_in, const int* in_sizes, int n_in,
                              void* d_out, int out_size, void* d_ws, size_t ws_size,
                              hipStream_t stream) {
    const float* feat = (const float*)d_in[0];
    const int* l = (const int*)d_in[1];
    const int* r = (const int*)d_in[2];
    // d_in[3] = T scalar (fixed 8192)
    const float* W1 = (const float*)d_in[4];
    const float* b1 = (const float*)d_in[5];
    const float* W2 = (const float*)d_in[6];
    const float* b2 = (const float*)d_in[7];

    char* ws = (char*)d_ws;
    // layout (bytes):
    //   cs_t   : [0, 16779264)                  (8193*512*4)
    //   e      : [16779264, 50333696)           (16384*1024*2)
    //   h      : [50333696, 83888128)           (16384*1024*2)  -- aliased with cs_inc
    //   cs_inc : [50333696, 67110912)           (512*8192*4)    dead before h written
    //   W1b    : [83888128, 85985280)           (1024*1024*2)
    //   W2b    : [85985280, 87033856)           (512*1024*2)
    float* cs_t = (float*)ws;
    __hip_bfloat16* e = (__hip_bfloat16*)(ws + 16779264);
    __hip_bfloat16* h = (__hip_bfloat16*)(ws + 50333696);
    float* cs_inc = (float*)(ws + 50333696);
    __hip_bfloat16* W1b = (__hip_bfloat16*)(ws + 83888128);
    __hip_bfloat16* W2b = (__hip_bfloat16*)(ws + 85985280);

    const int ncvt = (HID_DIM * K2C + OUT_DIM * HID_DIM) / 4 / 256;  // 1536 blocks
    cvt_bf16_kernel<<<dim3(ncvt), 256, 0, stream>>>(W1, W2, W1b, W2b);
    cumsum_kernel<<<dim3(C_DIM), 64, 0, stream>>>(feat, cs_inc);
    transpose_kernel<<<dim3((T_SEQ + 32) / 32, C_DIM / 32), dim3(32, 8), 0, stream>>>(cs_inc, cs_t);
    pool_kernel<<<dim3(N_PROP), 512, 0, stream>>>(cs_t, l, r, e);

    // GEMM1: (16384 x 1024) = e (16384,1024) x W1b (1024,1024)^T, relu -> bf16 h
    gemm2p_kernel<256, 256, 2, 4, 1>
        <<<dim3((N_PROP / 256) * (HID_DIM / 256)), 512, 0, stream>>>(e, W1b, b1, h, HID_DIM, K2C, HID_DIM / 256);
    // GEMM2: (16384 x 512) = h (16384,1024) x W2b (512,1024)^T -> fp32 d_out
    gemm2p_kernel<256, 128, 4, 2, 0>
        <<<dim3((N_PROP / 256) * (OUT_DIM / 128)), 512, 0, stream>>>(h, W2b, b2, d_out, OUT_DIM, HID_DIM, OUT_DIM / 128);
}

// Round 3
// 117.792 us; speedup vs baseline: 1.3930x; 1.1217x over previous
//
#include <hip/hip_runtime.h>
#include <hip/hip_bf16.h>
#include <stdint.h>

#define C_DIM 512
#define T_SEQ 8192
#define N_PROP 16384
#define HID_DIM 1024
#define OUT_DIM 512
#define K2C 1024  // 2*C

typedef __attribute__((ext_vector_type(8))) __bf16 bf16x8;
typedef __attribute__((ext_vector_type(4))) float f32x4;

#define CFENCE() asm volatile("" ::: "memory")

// ---------------- cumsum: one wave per channel, float4 chunks, shuffle scan ----------------
__global__ __launch_bounds__(64) void cumsum_kernel(const float* __restrict__ feat,
                                                    float* __restrict__ cs_inc) {
    int c = blockIdx.x;
    const float4* in = (const float4*)(feat + (size_t)c * T_SEQ);
    float4* out = (float4*)(cs_inc + (size_t)c * T_SEQ);
    int lane = threadIdx.x;
    float carry = 0.0f;
    for (int i0 = 0; i0 < T_SEQ / 4; i0 += 64) {
        float4 v = in[i0 + lane];
        float s1 = v.x + v.y;
        float s2 = s1 + v.z;
        float s3 = s2 + v.w;
        float x = s3;
#pragma unroll
        for (int s = 1; s < 64; s <<= 1) {
            float y = __shfl_up(x, s);
            if (lane >= s) x += y;
        }
        float base = carry + (x - s3);
        float4 o;
        o.x = base + v.x; o.y = base + s1; o.z = base + s2; o.w = base + s3;
        out[i0 + lane] = o;
        carry += __shfl(x, 63);
    }
}

// ---------------- transpose cs_inc (C, T) -> cs_t (T+1, C) with leading-zero shift ----------------
__global__ __launch_bounds__(256) void transpose_kernel(const float* __restrict__ cs_inc,
                                                        float* __restrict__ cs_t) {
    __shared__ float tl[32][33];
    int tx = threadIdx.x, ty = threadIdx.y;  // (32, 8)
    int x0 = blockIdx.x * 32;
    int y0 = blockIdx.y * 32;
#pragma unroll
    for (int i = 0; i < 32; i += 8) {
        int t = x0 + tx;
        int ch = y0 + ty + i;
        float v = 0.0f;
        if (t >= 1 && t <= T_SEQ) v = cs_inc[(size_t)ch * T_SEQ + (t - 1)];
        tl[ty + i][tx] = v;
    }
    __syncthreads();
#pragma unroll
    for (int i = 0; i < 32; i += 8) {
        int t = x0 + ty + i;
        int ch = y0 + tx;
        if (t <= T_SEQ) cs_t[(size_t)t * C_DIM + ch] = tl[tx][ty + i];
    }
}

// ---------------- pooling -> e (N, 2C) bf16; 4 proposals/block, float4/thread ----------------
__global__ __launch_bounds__(512) void pool_kernel(const float* __restrict__ cs_t,
                                                   const int* __restrict__ lptr,
                                                   const int* __restrict__ rptr,
                                                   __hip_bfloat16* __restrict__ e) {
    int n = blockIdx.x * 4 + (threadIdx.x >> 7);
    int c4 = (threadIdx.x & 127) * 4;
    int li = lptr[n], ri = rptr[n];
    float w = fmaxf((float)(ri - li), 1.0f);
    int bw = max(1, (int)(0.15f * w));
    int lb_s = max(0, li - bw);
    int lb_e = min(T_SEQ, li + bw);
    int rb_s = max(0, ri - bw);
    int rb_e = min(T_SEQ, ri + bw);
    lb_e = min(max(lb_s + 1, lb_e), T_SEQ);
    rb_e = min(max(rb_s + 1, rb_e), T_SEQ);
    float4 a = *(const float4*)(cs_t + (size_t)lb_e * C_DIM + c4);
    float4 b = *(const float4*)(cs_t + (size_t)lb_s * C_DIM + c4);
    float4 cc = *(const float4*)(cs_t + (size_t)rb_e * C_DIM + c4);
    float4 d = *(const float4*)(cs_t + (size_t)rb_s * C_DIM + c4);
    float rl = 1.0f / (float)(lb_e - lb_s);
    float rr = 1.0f / (float)(rb_e - rb_s);
    __hip_bfloat16 L0 = __float2bfloat16((a.x - b.x) * rl);
    __hip_bfloat16 L1 = __float2bfloat16((a.y - b.y) * rl);
    __hip_bfloat16 L2 = __float2bfloat16((a.z - b.z) * rl);
    __hip_bfloat16 L3 = __float2bfloat16((a.w - b.w) * rl);
    __hip_bfloat16 R0 = __float2bfloat16((cc.x - d.x) * rr);
    __hip_bfloat16 R1 = __float2bfloat16((cc.y - d.y) * rr);
    __hip_bfloat16 R2 = __float2bfloat16((cc.z - d.z) * rr);
    __hip_bfloat16 R3 = __float2bfloat16((cc.w - d.w) * rr);
    ushort4 ul, ur;
    ul.x = *(unsigned short*)&L0; ul.y = *(unsigned short*)&L1;
    ul.z = *(unsigned short*)&L2; ul.w = *(unsigned short*)&L3;
    ur.x = *(unsigned short*)&R0; ur.y = *(unsigned short*)&R1;
    ur.z = *(unsigned short*)&R2; ur.w = *(unsigned short*)&R3;
    *(ushort4*)(e + (size_t)n * K2C + c4) = ul;
    *(ushort4*)(e + (size_t)n * K2C + C_DIM + c4) = ur;
}

// ---------------- fused fp32 -> bf16 convert for W1 and W2 ----------------
__global__ __launch_bounds__(256) void cvt_bf16_kernel(const float* __restrict__ W1,
                                                       const float* __restrict__ W2,
                                                       __hip_bfloat16* __restrict__ W1b,
                                                       __hip_bfloat16* __restrict__ W2b) {
    const int n1 = HID_DIM * K2C;
    int i = (blockIdx.x * 256 + threadIdx.x) * 4;
    const float* src;
    __hip_bfloat16* dst;
    int j;
    if (i < n1) { src = W1; dst = W1b; j = i; }
    else        { src = W2; dst = W2b; j = i - n1; }
    float4 v = *(const float4*)(src + j);
    __hip_bfloat16 h0 = __float2bfloat16(v.x);
    __hip_bfloat16 h1 = __float2bfloat16(v.y);
    __hip_bfloat16 h2 = __float2bfloat16(v.z);
    __hip_bfloat16 h3 = __float2bfloat16(v.w);
    ushort4 u;
    u.x = *(unsigned short*)&h0; u.y = *(unsigned short*)&h1;
    u.z = *(unsigned short*)&h2; u.w = *(unsigned short*)&h3;
    *(ushort4*)(dst + j) = u;
}

// ---------------- pipelined GEMM: counted-vmcnt + XOR-swizzled LDS ----------------
// C[m][n] = sum_k A[m][k]*B[n][k] (+bias, optional relu->bf16).
// BK=64, 512 threads = 8 waves (WM x WN). Double-buffered K-tiles.
// Per tile: [stageA(t+1); vmcnt(LA); s_barrier; kk0: ds_read+MFMA;
//            stageB(t+1); kk1: ds_read+MFMA; s_barrier]
// Never drains vmcnt to 0 in the main loop; B(t) has ~1 phase of in-flight
// slack, A(t+1) a full tile.
// LDS swizzle: linear gload_lds dest + pre-swizzled global source granule
// (schunk = (tid&7)^(row&7)) + same XOR on ds_read (elem ^= (row&7)*8).
template <int BM, int BN, int WM, int WN, int RELU_BF16>
__global__ __launch_bounds__(512, 2) void gemm_pipe_kernel(const __hip_bfloat16* __restrict__ A,
                                                           const __hip_bfloat16* __restrict__ B,
                                                           const float* __restrict__ bias,
                                                           void* __restrict__ Cout,
                                                           int Nc, int K, int NBlk) {
    constexpr int BK = 64;
    constexpr int WMT = BM / WM;
    constexpr int WNT = BN / WN;
    constexpr int MR = WMT / 16;
    constexpr int NR = WNT / 16;
    constexpr int LA = BM / 64;  // gload_lds per thread for A-tile
    constexpr int LB = BN / 64;

    __shared__ __align__(16) __hip_bfloat16 As[2][BM * BK];
    __shared__ __align__(16) __hip_bfloat16 Bs[2][BN * BK];

    const int tid = threadIdx.x;
    const int lane = tid & 63;
    const int wid = tid >> 6;
    const int wm = wid / WN;
    const int wn = wid % WN;

    const int nwg = gridDim.x;  // multiple of 8 for both instantiations
    const int wg = (blockIdx.x & 7) * (nwg >> 3) + (blockIdx.x >> 3);
    const long m0 = (long)(wg / NBlk) * BM;
    const long n0 = (long)(wg % NBlk) * BN;

    const int srow = tid >> 3;                  // row within 64-row staging group
    const int schunk = (tid & 7) ^ (srow & 7);  // pre-swizzled 16B source granule
    const int fr = lane & 15;
    const int g8 = (lane >> 4) * 8;             // lane-group element offset

    f32x4 acc[MR][NR] = {};

    auto stageA = [&](int s, int k0) {
#pragma unroll
        for (int i = 0; i < LA; ++i)
            __builtin_amdgcn_global_load_lds(
                (const __attribute__((address_space(1))) void*)(A + (m0 + i * 64 + srow) * K + k0 + schunk * 8),
                (__attribute__((address_space(3))) void*)(&As[s][i * 4096 + tid * 8]), 16, 0, 0);
    };
    auto stageB = [&](int s, int k0) {
#pragma unroll
        for (int i = 0; i < LB; ++i)
            __builtin_amdgcn_global_load_lds(
                (const __attribute__((address_space(1))) void*)(B + (n0 + i * 64 + srow) * K + k0 + schunk * 8),
                (__attribute__((address_space(3))) void*)(&Bs[s][i * 4096 + tid * 8]), 16, 0, 0);
    };
    // swizzled LDS fragment read: logical (row, kk*32 + g8 .. +7)
    auto ldfrag = [&](const __hip_bfloat16* buf, int row, int kbase) -> bf16x8 {
        return *(const bf16x8*)(buf + row * 64 + ((kbase + g8) ^ ((row & 7) * 8)));
    };

    const int NT = K / BK;
    stageA(0, 0);
    stageB(0, 0);
    for (int t = 0; t < NT; ++t) {
        const int cur = t & 1;
        const __hip_bfloat16* Asc = &As[cur][0];
        const __hip_bfloat16* Bsc = &Bs[cur][0];
        if (t + 1 < NT) {
            stageA(cur ^ 1, (t + 1) * BK);
            asm volatile("s_waitcnt vmcnt(%0)" ::"n"(LA) : "memory");
        } else {
            asm volatile("s_waitcnt vmcnt(0)" ::: "memory");
        }
        __builtin_amdgcn_s_barrier();
        CFENCE();
        // ---- kk = 0 ----
        {
            bf16x8 af[MR], bv[NR];
#pragma unroll
            for (int m = 0; m < MR; ++m) af[m] = ldfrag(Asc, wm * WMT + m * 16 + fr, 0);
#pragma unroll
            for (int n = 0; n < NR; ++n) bv[n] = ldfrag(Bsc, wn * WNT + n * 16 + fr, 0);
            __builtin_amdgcn_s_setprio(1);
#pragma unroll
            for (int m = 0; m < MR; ++m)
#pragma unroll
                for (int n = 0; n < NR; ++n)
                    acc[m][n] = __builtin_amdgcn_mfma_f32_16x16x32_bf16(af[m], bv[n], acc[m][n], 0, 0, 0);
            __builtin_amdgcn_s_setprio(0);
        }
        // ---- mid-tile: stage next B ----
        if (t + 1 < NT) stageB(cur ^ 1, (t + 1) * BK);
        // ---- kk = 1 ----
        {
            bf16x8 af[MR], bv[NR];
#pragma unroll
            for (int m = 0; m < MR; ++m) af[m] = ldfrag(Asc, wm * WMT + m * 16 + fr, 32);
#pragma unroll
            for (int n = 0; n < NR; ++n) bv[n] = ldfrag(Bsc, wn * WNT + n * 16 + fr, 32);
            __builtin_amdgcn_s_setprio(1);
#pragma unroll
            for (int m = 0; m < MR; ++m)
#pragma unroll
                for (int n = 0; n < NR; ++n)
                    acc[m][n] = __builtin_amdgcn_mfma_f32_16x16x32_bf16(af[m], bv[n], acc[m][n], 0, 0, 0);
            __builtin_amdgcn_s_setprio(0);
        }
        CFENCE();
        __builtin_amdgcn_s_barrier();
    }

    const int rq = (lane >> 4) * 4;
#pragma unroll
    for (int m = 0; m < MR; ++m)
#pragma unroll
        for (int n = 0; n < NR; ++n) {
            long col = n0 + wn * WNT + n * 16 + fr;
            float bb = bias[col];
#pragma unroll
            for (int q = 0; q < 4; ++q) {
                long row = m0 + wm * WMT + m * 16 + rq + q;
                float v = acc[m][n][q] + bb;
                if (RELU_BF16) {
                    v = fmaxf(v, 0.0f);
                    ((__hip_bfloat16*)Cout)[row * Nc + col] = __float2bfloat16(v);
                } else {
                    ((float*)Cout)[row * Nc + col] = v;
                }
            }
        }
}

extern "C" void kernel_launch(void* const* d_in, const int* in_sizes, int n_in,
                              void* d_out, int out_size, void* d_ws, size_t ws_size,
                              hipStream_t stream) {
    const float* feat = (const float*)d_in[0];
    const int* l = (const int*)d_in[1];
    const int* r = (const int*)d_in[2];
    const float* W1 = (const float*)d_in[4];
    const float* b1 = (const float*)d_in[5];
    const float* W2 = (const float*)d_in[6];
    const float* b2 = (const float*)d_in[7];

    char* ws = (char*)d_ws;
    float* cs_t = (float*)ws;                                    // 8193*512*4
    __hip_bfloat16* e = (__hip_bfloat16*)(ws + 16779264);        // 16384*1024*2
    __hip_bfloat16* h = (__hip_bfloat16*)(ws + 50333696);        // 16384*1024*2 (aliases cs_inc)
    float* cs_inc = (float*)(ws + 50333696);                     // 512*8192*4, dead before h
    __hip_bfloat16* W1b = (__hip_bfloat16*)(ws + 83888128);      // 1024*1024*2
    __hip_bfloat16* W2b = (__hip_bfloat16*)(ws + 85985280);      // 512*1024*2

    const int ncvt = (HID_DIM * K2C + OUT_DIM * HID_DIM) / 4 / 256;
    cvt_bf16_kernel<<<dim3(ncvt), 256, 0, stream>>>(W1, W2, W1b, W2b);
    cumsum_kernel<<<dim3(C_DIM), 64, 0, stream>>>(feat, cs_inc);
    transpose_kernel<<<dim3((T_SEQ + 32) / 32, C_DIM / 32), dim3(32, 8), 0, stream>>>(cs_inc, cs_t);
    pool_kernel<<<dim3(N_PROP / 4), 512, 0, stream>>>(cs_t, l, r, e);

    gemm_pipe_kernel<256, 256, 2, 4, 1>
        <<<dim3((N_PROP / 256) * (HID_DIM / 256)), 512, 0, stream>>>(e, W1b, b1, h, HID_DIM, K2C, HID_DIM / 256);
    gemm_pipe_kernel<256, 128, 4, 2, 0>
        <<<dim3((N_PROP / 256) * (OUT_DIM / 128)), 512, 0, stream>>>(h, W2b, b2, d_out, OUT_DIM, HID_DIM, OUT_DIM / 128);
}

// Round 5
// 113.075 us; speedup vs baseline: 1.4511x; 1.0417x over previous
//
#include <hip/hip_runtime.h>
#include <hip/hip_bf16.h>
#include <stdint.h>

#define C_DIM 512
#define T_SEQ 8192
#define N_PROP 16384
#define HID_DIM 1024
#define OUT_DIM 512
#define K2C 1024  // 2*C

typedef __attribute__((ext_vector_type(8))) __bf16 bf16x8;
typedef __attribute__((ext_vector_type(4))) float f32x4;

// ---------------- cumsum: one wave per channel, float4 chunks, shuffle scan ----------------
__global__ __launch_bounds__(64) void cumsum_kernel(const float* __restrict__ feat,
                                                    float* __restrict__ cs_inc) {
    int c = blockIdx.x;
    const float4* in = (const float4*)(feat + (size_t)c * T_SEQ);
    float4* out = (float4*)(cs_inc + (size_t)c * T_SEQ);
    int lane = threadIdx.x;
    float carry = 0.0f;
    for (int i0 = 0; i0 < T_SEQ / 4; i0 += 64) {
        float4 v = in[i0 + lane];
        float s1 = v.x + v.y;
        float s2 = s1 + v.z;
        float s3 = s2 + v.w;
        float x = s3;
#pragma unroll
        for (int s = 1; s < 64; s <<= 1) {
            float y = __shfl_up(x, s);
            if (lane >= s) x += y;
        }
        float base = carry + (x - s3);
        float4 o;
        o.x = base + v.x; o.y = base + s1; o.z = base + s2; o.w = base + s3;
        out[i0 + lane] = o;
        carry += __shfl(x, 63);
    }
}

// ---------------- transpose cs_inc (C, T) -> cs_t (T+1, C) with leading-zero shift ----------------
__global__ __launch_bounds__(256) void transpose_kernel(const float* __restrict__ cs_inc,
                                                        float* __restrict__ cs_t) {
    __shared__ float tl[32][33];
    int tx = threadIdx.x, ty = threadIdx.y;  // (32, 8)
    int x0 = blockIdx.x * 32;
    int y0 = blockIdx.y * 32;
#pragma unroll
    for (int i = 0; i < 32; i += 8) {
        int t = x0 + tx;
        int ch = y0 + ty + i;
        float v = 0.0f;
        if (t >= 1 && t <= T_SEQ) v = cs_inc[(size_t)ch * T_SEQ + (t - 1)];
        tl[ty + i][tx] = v;
    }
    __syncthreads();
#pragma unroll
    for (int i = 0; i < 32; i += 8) {
        int t = x0 + ty + i;
        int ch = y0 + tx;
        if (t <= T_SEQ) cs_t[(size_t)t * C_DIM + ch] = tl[tx][ty + i];
    }
}

// ---------------- pooling -> e (N, 2C) bf16; 4 proposals/block, float4/thread ----------------
__global__ __launch_bounds__(512) void pool_kernel(const float* __restrict__ cs_t,
                                                   const int* __restrict__ lptr,
                                                   const int* __restrict__ rptr,
                                                   __hip_bfloat16* __restrict__ e) {
    int n = blockIdx.x * 4 + (threadIdx.x >> 7);
    int c4 = (threadIdx.x & 127) * 4;
    int li = lptr[n], ri = rptr[n];
    float w = fmaxf((float)(ri - li), 1.0f);
    int bw = max(1, (int)(0.15f * w));
    int lb_s = max(0, li - bw);
    int lb_e = min(T_SEQ, li + bw);
    int rb_s = max(0, ri - bw);
    int rb_e = min(T_SEQ, ri + bw);
    lb_e = min(max(lb_s + 1, lb_e), T_SEQ);
    rb_e = min(max(rb_s + 1, rb_e), T_SEQ);
    float4 a = *(const float4*)(cs_t + (size_t)lb_e * C_DIM + c4);
    float4 b = *(const float4*)(cs_t + (size_t)lb_s * C_DIM + c4);
    float4 cc = *(const float4*)(cs_t + (size_t)rb_e * C_DIM + c4);
    float4 d = *(const float4*)(cs_t + (size_t)rb_s * C_DIM + c4);
    float rl = 1.0f / (float)(lb_e - lb_s);
    float rr = 1.0f / (float)(rb_e - rb_s);
    __hip_bfloat16 L0 = __float2bfloat16((a.x - b.x) * rl);
    __hip_bfloat16 L1 = __float2bfloat16((a.y - b.y) * rl);
    __hip_bfloat16 L2 = __float2bfloat16((a.z - b.z) * rl);
    __hip_bfloat16 L3 = __float2bfloat16((a.w - b.w) * rl);
    __hip_bfloat16 R0 = __float2bfloat16((cc.x - d.x) * rr);
    __hip_bfloat16 R1 = __float2bfloat16((cc.y - d.y) * rr);
    __hip_bfloat16 R2 = __float2bfloat16((cc.z - d.z) * rr);
    __hip_bfloat16 R3 = __float2bfloat16((cc.w - d.w) * rr);
    ushort4 ul, ur;
    ul.x = *(unsigned short*)&L0; ul.y = *(unsigned short*)&L1;
    ul.z = *(unsigned short*)&L2; ul.w = *(unsigned short*)&L3;
    ur.x = *(unsigned short*)&R0; ur.y = *(unsigned short*)&R1;
    ur.z = *(unsigned short*)&R2; ur.w = *(unsigned short*)&R3;
    *(ushort4*)(e + (size_t)n * K2C + c4) = ul;
    *(ushort4*)(e + (size_t)n * K2C + C_DIM + c4) = ur;
}

// ---------------- fused fp32 -> bf16 convert for W1 and W2 ----------------
__global__ __launch_bounds__(256) void cvt_bf16_kernel(const float* __restrict__ W1,
                                                       const float* __restrict__ W2,
                                                       __hip_bfloat16* __restrict__ W1b,
                                                       __hip_bfloat16* __restrict__ W2b) {
    const int n1 = HID_DIM * K2C;
    int i = (blockIdx.x * 256 + threadIdx.x) * 4;
    const float* src;
    __hip_bfloat16* dst;
    int j;
    if (i < n1) { src = W1; dst = W1b; j = i; }
    else        { src = W2; dst = W2b; j = i - n1; }
    float4 v = *(const float4*)(src + j);
    __hip_bfloat16 h0 = __float2bfloat16(v.x);
    __hip_bfloat16 h1 = __float2bfloat16(v.y);
    __hip_bfloat16 h2 = __float2bfloat16(v.z);
    __hip_bfloat16 h3 = __float2bfloat16(v.w);
    ushort4 u;
    u.x = *(unsigned short*)&h0; u.y = *(unsigned short*)&h1;
    u.z = *(unsigned short*)&h2; u.w = *(unsigned short*)&h3;
    *(ushort4*)(dst + j) = u;
}

// ---------------- 8-phase-style counted-vmcnt GEMM (T2+T3+T4+T5) ----------------
// C[m][n] = sum_k A[m][k]*B[n][k] (+bias, optional relu->bf16). BK=64, 512 thr = 8 waves.
// RACE-FIX vs R4: the counted vmcnt wait is placed BEFORE the tile's closing barrier
// (wait-then-barrier discipline). vmcnt is per-wave; only [own-wait -> shared barrier]
// publishes "tile u+1 landed" to all waves before anyone ds_reads it.
// Ledger (MQ=2): tile u's 8 loads issued at (u-2,p3):{0,1} + (u-1,p0/p1/p2):{2,3}{4,5}{6,7}.
//   At (u,p3): outstanding = (u+1){2..7} + (u+2){0,1}; vmcnt(2) -> tile u+1 fully landed.
// Ledger (MQ=1): tile u's 6 loads at (u-2,p1):{0,1,2} + (u-1,p0):{3,4,5}.
//   At (u,p1): outstanding = (u+1){3,4,5} + (u+2){0,1,2}; vmcnt(3) -> tile u+1 landed.
// Tail: at u==NT-2 the next-next stage is skipped, so wait vmcnt(0) there instead.
template <int BM, int BN, int WM, int WN, int MQ, int RELU_BF16>
__global__ __launch_bounds__(512, 2) void gemm8p_kernel(const __hip_bfloat16* __restrict__ A,
                                                        const __hip_bfloat16* __restrict__ B,
                                                        const float* __restrict__ bias,
                                                        void* __restrict__ Cout,
                                                        int Nc, int K, int NBlk) {
    constexpr int BK = 64;
    constexpr int WMT = BM / WM, WNT = BN / WN;
    constexpr int MR = WMT / 16, NR = WNT / 16;
    constexpr int LA = BM / 64, LB = BN / 64;
    constexpr int U = LA + LB;
    constexpr int CL = (MQ == 2) ? 2 : 3;  // loads issued in a tile's last phase

    __shared__ __align__(16) __hip_bfloat16 As[2][BM * BK];
    __shared__ __align__(16) __hip_bfloat16 Bs[2][BN * BK];

    const int tid = threadIdx.x;
    const int lane = tid & 63;
    const int wid = tid >> 6;
    const int wm = wid / WN;
    const int wn = wid % WN;

    const int nwg = gridDim.x;  // 256 for both instantiations (multiple of 8)
    const int wg = (blockIdx.x & 7) * (nwg >> 3) + (blockIdx.x >> 3);
    const long m0 = (long)(wg / NBlk) * BM;
    const long n0 = (long)(wg % NBlk) * BN;

    const int srow = tid >> 3;                  // row within 64-row staging round
    const int schunk = (tid & 7) ^ (srow & 7);  // pre-swizzled 16B source granule
    const int fr = lane & 15;
    const int g8 = (lane >> 4) * 8;

    f32x4 acc[MR][NR] = {};

    auto stage_one = [&](int s, int k0, int i) {
        if (i < LA)
            __builtin_amdgcn_global_load_lds(
                (const __attribute__((address_space(1))) void*)(A + (m0 + i * 64 + srow) * K + k0 + schunk * 8),
                (__attribute__((address_space(3))) void*)(&As[s][i * 4096 + tid * 8]), 16, 0, 0);
        else
            __builtin_amdgcn_global_load_lds(
                (const __attribute__((address_space(1))) void*)(B + (n0 + (i - LA) * 64 + srow) * K + k0 + schunk * 8),
                (__attribute__((address_space(3))) void*)(&Bs[s][(i - LA) * 4096 + tid * 8]), 16, 0, 0);
    };
    auto ldfragA = [&](int s, int row, int kbase) -> bf16x8 {
        return *(const bf16x8*)(&As[s][row * 64 + ((kbase + g8) ^ ((row & 7) * 8))]);
    };
    auto ldfragB = [&](int s, int row, int kbase) -> bf16x8 {
        return *(const bf16x8*)(&Bs[s][row * 64 + ((kbase + g8) ^ ((row & 7) * 8))]);
    };

    const int NT = K / BK;

    // prologue: tile0 fully + tile1's first CL loads; publish tile0 to all waves
#pragma unroll
    for (int i = 0; i < U; ++i) stage_one(0, 0, i);
#pragma unroll
    for (int i = 0; i < CL; ++i) stage_one(1, BK, i);
    asm volatile("s_waitcnt vmcnt(%0)" ::"n"(CL) : "memory");
    __builtin_amdgcn_s_barrier();

    for (int u = 0; u < NT; ++u) {
        const int cur = u & 1;
        if constexpr (MQ == 2) {
            // ---------------- phase 0 (kk0, mq0) ----------------
            bf16x8 af[MR], bv[NR];
#pragma unroll
            for (int m = 0; m < MR; ++m) af[m] = ldfragA(cur, wm * WMT + m * 16 + fr, 0);
#pragma unroll
            for (int n = 0; n < NR; ++n) bv[n] = ldfragB(cur, wn * WNT + n * 16 + fr, 0);
            if (u + 1 < NT) { stage_one(cur ^ 1, (u + 1) * BK, 2); stage_one(cur ^ 1, (u + 1) * BK, 3); }
            __builtin_amdgcn_s_barrier();
            asm volatile("s_waitcnt lgkmcnt(0)" ::: "memory");
            __builtin_amdgcn_sched_barrier(0);
            __builtin_amdgcn_s_setprio(1);
#pragma unroll
            for (int m = 0; m < MR / 2; ++m)
#pragma unroll
                for (int n = 0; n < NR; ++n)
                    acc[m][n] = __builtin_amdgcn_mfma_f32_16x16x32_bf16(af[m], bv[n], acc[m][n], 0, 0, 0);
            __builtin_amdgcn_s_setprio(0);
            __builtin_amdgcn_s_barrier();
            // ---------------- phase 1 (kk0, mq1) ----------------
            if (u + 1 < NT) { stage_one(cur ^ 1, (u + 1) * BK, 4); stage_one(cur ^ 1, (u + 1) * BK, 5); }
            __builtin_amdgcn_s_barrier();
            __builtin_amdgcn_s_setprio(1);
#pragma unroll
            for (int m = MR / 2; m < MR; ++m)
#pragma unroll
                for (int n = 0; n < NR; ++n)
                    acc[m][n] = __builtin_amdgcn_mfma_f32_16x16x32_bf16(af[m], bv[n], acc[m][n], 0, 0, 0);
            __builtin_amdgcn_s_setprio(0);
            __builtin_amdgcn_s_barrier();
            // ---------------- phase 2 (kk1, mq0) ----------------
#pragma unroll
            for (int m = 0; m < MR; ++m) af[m] = ldfragA(cur, wm * WMT + m * 16 + fr, 32);
#pragma unroll
            for (int n = 0; n < NR; ++n) bv[n] = ldfragB(cur, wn * WNT + n * 16 + fr, 32);
            if (u + 1 < NT) { stage_one(cur ^ 1, (u + 1) * BK, 6); stage_one(cur ^ 1, (u + 1) * BK, 7); }
            __builtin_amdgcn_s_barrier();
            asm volatile("s_waitcnt lgkmcnt(0)" ::: "memory");
            __builtin_amdgcn_sched_barrier(0);
            __builtin_amdgcn_s_setprio(1);
#pragma unroll
            for (int m = 0; m < MR / 2; ++m)
#pragma unroll
                for (int n = 0; n < NR; ++n)
                    acc[m][n] = __builtin_amdgcn_mfma_f32_16x16x32_bf16(af[m], bv[n], acc[m][n], 0, 0, 0);
            __builtin_amdgcn_s_setprio(0);
            __builtin_amdgcn_s_barrier();
            // ---------------- phase 3 (kk1, mq1) ----------------
            if (u + 2 < NT) { stage_one(cur, (u + 2) * BK, 0); stage_one(cur, (u + 2) * BK, 1); }
            // publish tile u+1: own-wait THEN shared barrier (race-fix)
            if (u + 2 < NT)
                asm volatile("s_waitcnt vmcnt(%0)" ::"n"(CL) : "memory");
            else if (u + 1 < NT)
                asm volatile("s_waitcnt vmcnt(0)" ::: "memory");
            __builtin_amdgcn_s_barrier();
            __builtin_amdgcn_s_setprio(1);
#pragma unroll
            for (int m = MR / 2; m < MR; ++m)
#pragma unroll
                for (int n = 0; n < NR; ++n)
                    acc[m][n] = __builtin_amdgcn_mfma_f32_16x16x32_bf16(af[m], bv[n], acc[m][n], 0, 0, 0);
            __builtin_amdgcn_s_setprio(0);
            __builtin_amdgcn_s_barrier();
        } else {
            // ---------------- MQ==1: phase 0 (kk0) ----------------
            bf16x8 af0[MR], af1[MR], bv0[NR], bv1[NR];
#pragma unroll
            for (int m = 0; m < MR; ++m) {
                af0[m] = ldfragA(cur, wm * WMT + m * 16 + fr, 0);
                af1[m] = ldfragA(cur, wm * WMT + m * 16 + fr, 32);
            }
#pragma unroll
            for (int n = 0; n < NR; ++n) {
                bv0[n] = ldfragB(cur, wn * WNT + n * 16 + fr, 0);
                bv1[n] = ldfragB(cur, wn * WNT + n * 16 + fr, 32);
            }
            if (u + 1 < NT) { stage_one(cur ^ 1, (u + 1) * BK, 3); stage_one(cur ^ 1, (u + 1) * BK, 4); stage_one(cur ^ 1, (u + 1) * BK, 5); }
            __builtin_amdgcn_s_barrier();
            asm volatile("s_waitcnt lgkmcnt(0)" ::: "memory");
            __builtin_amdgcn_sched_barrier(0);
            __builtin_amdgcn_s_setprio(1);
#pragma unroll
            for (int m = 0; m < MR; ++m)
#pragma unroll
                for (int n = 0; n < NR; ++n)
                    acc[m][n] = __builtin_amdgcn_mfma_f32_16x16x32_bf16(af0[m], bv0[n], acc[m][n], 0, 0, 0);
            __builtin_amdgcn_s_setprio(0);
            __builtin_amdgcn_s_barrier();
            // ---------------- phase 1 (kk1) ----------------
            if (u + 2 < NT) { stage_one(cur, (u + 2) * BK, 0); stage_one(cur, (u + 2) * BK, 1); stage_one(cur, (u + 2) * BK, 2); }
            // publish tile u+1 (race-fix)
            if (u + 2 < NT)
                asm volatile("s_waitcnt vmcnt(%0)" ::"n"(CL) : "memory");
            else if (u + 1 < NT)
                asm volatile("s_waitcnt vmcnt(0)" ::: "memory");
            __builtin_amdgcn_s_barrier();
            __builtin_amdgcn_s_setprio(1);
#pragma unroll
            for (int m = 0; m < MR; ++m)
#pragma unroll
                for (int n = 0; n < NR; ++n)
                    acc[m][n] = __builtin_amdgcn_mfma_f32_16x16x32_bf16(af1[m], bv1[n], acc[m][n], 0, 0, 0);
            __builtin_amdgcn_s_setprio(0);
            __builtin_amdgcn_s_barrier();
        }
    }

    const int rq = (lane >> 4) * 4;
#pragma unroll
    for (int m = 0; m < MR; ++m)
#pragma unroll
        for (int n = 0; n < NR; ++n) {
            long col = n0 + wn * WNT + n * 16 + fr;
            float bb = bias[col];
#pragma unroll
            for (int q = 0; q < 4; ++q) {
                long row = m0 + wm * WMT + m * 16 + rq + q;
                float v = acc[m][n][q] + bb;
                if (RELU_BF16) {
                    v = fmaxf(v, 0.0f);
                    ((__hip_bfloat16*)Cout)[row * Nc + col] = __float2bfloat16(v);
                } else {
                    ((float*)Cout)[row * Nc + col] = v;
                }
            }
        }
}

extern "C" void kernel_launch(void* const* d_in, const int* in_sizes, int n_in,
                              void* d_out, int out_size, void* d_ws, size_t ws_size,
                              hipStream_t stream) {
    const float* feat = (const float*)d_in[0];
    const int* l = (const int*)d_in[1];
    const int* r = (const int*)d_in[2];
    const float* W1 = (const float*)d_in[4];
    const float* b1 = (const float*)d_in[5];
    const float* W2 = (const float*)d_in[6];
    const float* b2 = (const float*)d_in[7];

    char* ws = (char*)d_ws;
    float* cs_t = (float*)ws;                                    // 8193*512*4
    __hip_bfloat16* e = (__hip_bfloat16*)(ws + 16779264);        // 16384*1024*2
    __hip_bfloat16* h = (__hip_bfloat16*)(ws + 50333696);        // 16384*1024*2 (aliases cs_inc)
    float* cs_inc = (float*)(ws + 50333696);                     // 512*8192*4, dead before h
    __hip_bfloat16* W1b = (__hip_bfloat16*)(ws + 83888128);      // 1024*1024*2
    __hip_bfloat16* W2b = (__hip_bfloat16*)(ws + 85985280);      // 512*1024*2

    const int ncvt = (HID_DIM * K2C + OUT_DIM * HID_DIM) / 4 / 256;
    cvt_bf16_kernel<<<dim3(ncvt), 256, 0, stream>>>(W1, W2, W1b, W2b);
    cumsum_kernel<<<dim3(C_DIM), 64, 0, stream>>>(feat, cs_inc);
    transpose_kernel<<<dim3((T_SEQ + 32) / 32, C_DIM / 32), dim3(32, 8), 0, stream>>>(cs_inc, cs_t);
    pool_kernel<<<dim3(N_PROP / 4), 512, 0, stream>>>(cs_t, l, r, e);

    // GEMM1: h = relu(e @ W1^T + b1), 16384x1024, K=1024. 256x256 tile, waves 2x4, MQ=2.
    gemm8p_kernel<256, 256, 2, 4, 2, 1>
        <<<dim3((N_PROP / 256) * (HID_DIM / 256)), 512, 0, stream>>>(e, W1b, b1, h, HID_DIM, K2C, HID_DIM / 256);
    // GEMM2: out = h @ W2^T + b2, 16384x512, K=1024. 256x128 tile, waves 4x2, MQ=1.
    gemm8p_kernel<256, 128, 4, 2, 1, 0>
        <<<dim3((N_PROP / 256) * (OUT_DIM / 128)), 512, 0, stream>>>(h, W2b, b2, d_out, OUT_DIM, HID_DIM, OUT_DIM / 128);
}